// Round 1
// baseline (155.643 us; speedup 1.0000x reference)
//
#include <hip/hip_runtime.h>

#define COST_CLASS 1.0f
#define COST_BBOX  5.0f
#define COST_GIOU  2.0f
#define EPS 1e-6f

// Problem constants (from setup_inputs): B=32, Q=300, C=11, T=3200
constexpr int kC = 11;

// ---------------- Kernel A: per-prediction softmax ----------------
// One thread per prediction row. 9600 threads total; trivial cost.
__global__ void softmax_probs_kernel(const float* __restrict__ logits,
                                     float* __restrict__ probs, int N) {
    int n = blockIdx.x * blockDim.x + threadIdx.x;
    if (n >= N) return;
    float v[kC];
    float m = -1e30f;
#pragma unroll
    for (int c = 0; c < kC; ++c) {
        v[c] = logits[n * kC + c];
        m = fmaxf(m, v[c]);
    }
    float s = 0.f;
#pragma unroll
    for (int c = 0; c < kC; ++c) {
        v[c] = expf(v[c] - m);
        s += v[c];
    }
    float inv = 1.f / s;
#pragma unroll
    for (int c = 0; c < kC; ++c) probs[n * kC + c] = v[c] * inv;
}

// ---------------- Kernel B: cost matrix ----------------
// threadIdx.x -> target t (coalesced along output's contiguous dim)
// blockIdx.y  -> group of NPT predictions (block-uniform broadcast loads)
constexpr int TPB = 256;
constexpr int NPT = 8;

__global__ __launch_bounds__(TPB)
void cost_matrix_kernel(const float* __restrict__ probs,       // [N, C]
                        const float* __restrict__ pred_boxes,  // [N, 4] cxcywh
                        const int*   __restrict__ labels,      // [T]
                        const float* __restrict__ tboxes,      // [T, 4] cxcywh
                        float* __restrict__ out,               // [N, T]
                        int N, int T) {
    int t = blockIdx.x * TPB + threadIdx.x;
    if (t >= T) return;
    int n0 = blockIdx.y * NPT;

    // Target data -> registers (reused across NPT preds)
    float4 tb = ((const float4*)tboxes)[t];
    int lab = labels[t];
    float t_x0 = tb.x - 0.5f * tb.z;
    float t_y0 = tb.y - 0.5f * tb.w;
    float t_x1 = tb.x + 0.5f * tb.z;
    float t_y1 = tb.y + 0.5f * tb.w;
    float t_area = (t_x1 - t_x0) * (t_y1 - t_y0);

#pragma unroll
    for (int i = 0; i < NPT; ++i) {
        int n = n0 + i;
        float4 pb = ((const float4*)pred_boxes)[n];  // block-uniform broadcast
        float p_x0 = pb.x - 0.5f * pb.z;
        float p_y0 = pb.y - 0.5f * pb.w;
        float p_x1 = pb.x + 0.5f * pb.z;
        float p_y1 = pb.y + 0.5f * pb.w;
        float p_area = (p_x1 - p_x0) * (p_y1 - p_y0);

        // L1 on cxcywh
        float cb = fabsf(pb.x - tb.x) + fabsf(pb.y - tb.y) +
                   fabsf(pb.z - tb.z) + fabsf(pb.w - tb.w);

        // GIoU on xyxy
        float lt_x = fmaxf(p_x0, t_x0), lt_y = fmaxf(p_y0, t_y0);
        float rb_x = fminf(p_x1, t_x1), rb_y = fminf(p_y1, t_y1);
        float iw = fmaxf(rb_x - lt_x, 0.f), ih = fmaxf(rb_y - lt_y, 0.f);
        float inter = iw * ih;
        float uni = p_area + t_area - inter;
        float iou = inter / (uni + EPS);
        float cx0 = fminf(p_x0, t_x0), cy0 = fminf(p_y0, t_y0);
        float cx1 = fmaxf(p_x1, t_x1), cy1 = fmaxf(p_y1, t_y1);
        float cw = fmaxf(cx1 - cx0, 0.f), ch = fmaxf(cy1 - cy0, 0.f);
        float carea = cw * ch;
        float giou = iou - (carea - uni) / (carea + EPS);

        // cost_class: gather within one 44B row (L1 broadcast region per n)
        float cc = -probs[n * kC + lab];

        float cost = COST_CLASS * cc + COST_BBOX * cb + COST_GIOU * (-giou);
        out[(size_t)n * T + t] = cost;
    }
}

extern "C" void kernel_launch(void* const* d_in, const int* in_sizes, int n_in,
                              void* d_out, int out_size, void* d_ws, size_t ws_size,
                              hipStream_t stream) {
    const float* class_logits = (const float*)d_in[0];   // [B,Q,C]
    const float* bbox_coords  = (const float*)d_in[1];   // [B,Q,4]
    const int*   target_labels= (const int*)d_in[2];     // [T]
    const float* target_boxes = (const float*)d_in[3];   // [T,4]
    float* out = (float*)d_out;

    int N = in_sizes[0] / kC;      // B*Q = 9600
    int T = in_sizes[2];           // 3200

    float* probs = (float*)d_ws;   // N*C floats = 422 KB

    {
        int tpb = 256;
        int blocks = (N + tpb - 1) / tpb;
        softmax_probs_kernel<<<blocks, tpb, 0, stream>>>(class_logits, probs, N);
    }
    {
        dim3 grid((T + TPB - 1) / TPB, N / NPT);
        cost_matrix_kernel<<<grid, TPB, 0, stream>>>(probs, bbox_coords,
                                                     target_labels, target_boxes,
                                                     out, N, T);
    }
}